// Round 4
// baseline (184.102 us; speedup 1.0000x reference)
//
#include <hip/hip_runtime.h>
#include <stdint.h>

#define S 2048
#define D 256
#define H 8
#define HD 32
#define E_EDGES 65536
#define DFF 1024
#define M_TOK 8192   // B*S
#define CAP 512

typedef __attribute__((ext_vector_type(8))) short s16x8;
typedef __attribute__((ext_vector_type(8))) unsigned short u16x8;
typedef __attribute__((ext_vector_type(4))) float f32x4;

__device__ __forceinline__ float b2f(unsigned short u){
  union { unsigned int i; float f; } x; x.i = ((unsigned int)u) << 16; return x.f;
}
__device__ __forceinline__ unsigned short f2b(float f){
  union { float f; unsigned int i; } x; x.f = f;
  unsigned int r = x.i + 0x7fffu + ((x.i >> 16) & 1u);
  return (unsigned short)(r >> 16);
}

// ---------------- f32 -> bf16 conversion (weights) ------------------------------
__global__ __launch_bounds__(256) void cvt_kernel(
    const float* __restrict__ in, unsigned short* __restrict__ out, int n4)
{
  int i = blockIdx.x * 256 + threadIdx.x;
  if (i >= n4) return;
  const float4 v = *(const float4*)(in + (size_t)i * 4);
  unsigned short o[4] = { f2b(v.x), f2b(v.y), f2b(v.z), f2b(v.w) };
  *(uint2*)(out + (size_t)i * 4) = *(const uint2*)o;
}

// ---------------- LayerNorm (f32 input -> bf16 out), 1 wave per row ------------
__global__ __launch_bounds__(256) void ln_kernel(
    const float* __restrict__ xf,
    const float* __restrict__ g, const float* __restrict__ bt,
    unsigned short* __restrict__ out)
{
  const int wave = threadIdx.x >> 6;
  const int lane = threadIdx.x & 63;
  const int row = blockIdx.x * 4 + wave;
  const size_t base = (size_t)row * D + lane * 4;
  const float4 u = *(const float4*)(xf + base);
  float v[4] = { u.x, u.y, u.z, u.w };
  float s  = v[0]+v[1]+v[2]+v[3];
  float s2 = v[0]*v[0]+v[1]*v[1]+v[2]*v[2]+v[3]*v[3];
  #pragma unroll
  for (int off=32; off>=1; off>>=1){ s += __shfl_xor(s,off,64); s2 += __shfl_xor(s2,off,64); }
  const float mu  = s * (1.f/D);
  const float var = s2 * (1.f/D) - mu*mu;
  const float rs  = 1.f / sqrtf(var + 1e-5f);
  #pragma unroll
  for (int j=0;j<4;++j){
    const int c = lane*4 + j;
    const float y = (v[j]-mu)*rs*g[c] + bt[c];
    out[(size_t)row*D + c] = f2b(y);
  }
}

// ---------------- GEMM: C[M,N] = epi(A[MxK] * W[NxK]^T + bias) ------------------
__global__ __launch_bounds__(256) void gemm_kernel(
    const unsigned short* __restrict__ A,
    const unsigned short* __restrict__ W,
    const float* __restrict__ bias,
    unsigned short* __restrict__ outb,
    float* __restrict__ outf,
    const float* __restrict__ resf,
    int M, int N, int K, int act)
{
  __shared__ unsigned short As[64][40];
  __shared__ unsigned short Bs[64][40];
  const int tid  = threadIdx.x;
  const int wave = tid >> 6;
  const int lane = tid & 63;
  const int m0 = blockIdx.y * 64;
  const int n0 = blockIdx.x * 64;
  const int srow = tid >> 2;
  const int scol = (tid & 3) * 8;
  const int fr = lane & 15;
  const int kf = (lane >> 4) * 8;
  f32x4 acc[4];
  #pragma unroll
  for (int i=0;i<4;++i)
    #pragma unroll
    for (int r=0;r<4;++r) acc[i][r] = 0.f;

  for (int k0 = 0; k0 < K; k0 += 32) {
    *(u16x8*)&As[srow][scol] = *(const u16x8*)(A + (size_t)(m0+srow)*K + k0 + scol);
    *(u16x8*)&Bs[srow][scol] = *(const u16x8*)(W + (size_t)(n0+srow)*K + k0 + scol);
    __syncthreads();
    s16x8 bfrag = *(const s16x8*)&Bs[wave*16 + fr][kf];
    #pragma unroll
    for (int i = 0; i < 4; ++i) {
      s16x8 afrag = *(const s16x8*)&As[i*16 + fr][kf];
      acc[i] = __builtin_amdgcn_mfma_f32_16x16x32_bf16(afrag, bfrag, acc[i], 0, 0, 0);
    }
    __syncthreads();
  }
  const int col = n0 + wave*16 + fr;
  const float bvl = bias[col];
  const int rbase = (lane >> 4) * 4;
  #pragma unroll
  for (int i = 0; i < 4; ++i) {
    #pragma unroll
    for (int r = 0; r < 4; ++r) {
      const int row = m0 + i*16 + rbase + r;
      const size_t off = (size_t)row * N + col;
      float vv = acc[i][r] + bvl;
      if (act) vv = 0.5f * vv * (1.0f + erff(vv * 0.70710678118654752f));
      if (resf) vv += resf[off];
      if (outb) outb[off] = f2b(vv);
      if (outf) outf[off] = vv;
    }
  }
}

// ---------------- edge-bias scatter (np last-write-wins via packed atomicMax) ----
__global__ __launch_bounds__(256) void zero_kernel(uint4* __restrict__ p, int n4) {
  int i = blockIdx.x * 256 + threadIdx.x;
  if (i < n4) { uint4 z; z.x=0; z.y=0; z.z=0; z.w=0; p[i] = z; }
}
__global__ __launch_bounds__(256) void scatter_kernel(
    const int* __restrict__ ei, const float* __restrict__ attr,
    unsigned int* __restrict__ packed)
{
  int e = blockIdx.x * 256 + threadIdx.x;
  if (e >= E_EDGES) return;
  int r = ei[e], c = ei[E_EDGES + e];
  float v = attr[e];
  v = fminf(5.f, fmaxf(-5.f, v));
  unsigned int pk = (((unsigned int)e) << 16) | (unsigned int)f2b(v);
  atomicMax(&packed[(size_t)r * S + c], pk);
}

// ---------------- sparse masked attention: 1 block per (b, q-row) ---------------
// adj_mask arrives as int32 0/1 (harness integer contract)
__global__ __launch_bounds__(256) void attn_kernel(
    const unsigned short* __restrict__ qg,
    const unsigned short* __restrict__ kg,
    const unsigned short* __restrict__ vg,
    const int* __restrict__ mask,
    const unsigned int* __restrict__ packed,
    unsigned short* __restrict__ ctx)
{
  __shared__ unsigned short nidx[CAP];
  __shared__ float nbias[CAP];
  __shared__ float sc[H*CAP];
  __shared__ float qs[D];
  __shared__ int wtot[4], wbase[4], cnt_s;
  const int t = threadIdx.x;
  const int wave = t >> 6, lane = t & 63;
  const int bqi = blockIdx.x;          // b*S + qrow
  const int b = bqi >> 11;
  const int qrow = bqi & (S-1);
  qs[t] = b2f(qg[(size_t)bqi * D + t]);

  // deterministic mask-row compaction (mask = int32 0/1, 8 columns per thread)
  const int* mrow = mask + (size_t)bqi * S;
  const uint4 ma = *(const uint4*)(mrow + t*8);
  const uint4 mb = *(const uint4*)(mrow + t*8 + 4);
  unsigned int mv[8] = { ma.x, ma.y, ma.z, ma.w, mb.x, mb.y, mb.z, mb.w };
  int mycnt = 0;
  #pragma unroll
  for (int j = 0; j < 8; ++j) mycnt += mv[j] ? 1 : 0;
  int inc = mycnt;
  #pragma unroll
  for (int off=1; off<64; off<<=1){ int y = __shfl_up(inc, off, 64); if (lane >= off) inc += y; }
  if (lane == 63) wtot[wave] = inc;
  __syncthreads();
  if (t == 0) { int ss=0; for (int w=0; w<4; ++w){ wbase[w]=ss; ss+=wtot[w]; } cnt_s = ss; }
  __syncthreads();
  int pos = wbase[wave] + inc - mycnt;
  #pragma unroll
  for (int j = 0; j < 8; ++j) {
    if (mv[j]) {
      if (pos < CAP) nidx[pos] = (unsigned short)(t*8 + j);
      ++pos;
    }
  }
  __syncthreads();
  int cnt = cnt_s; if (cnt > CAP) cnt = CAP;

  for (int i = t; i < cnt; i += 256) {
    unsigned int pkv = packed[(size_t)qrow * S + nidx[i]];
    nbias[i] = b2f((unsigned short)(pkv & 0xffffu));   // empty slot -> bits 0 -> +0.0
  }
  __syncthreads();

  // scores for all (head, neighbor) pairs
  const float scale = 0.17677669529663687f;  // 1/sqrt(32)
  for (int i = t; i < cnt*H; i += 256) {
    const int h = i & 7, n = i >> 3;
    const int nk = nidx[n];
    const unsigned short* krow = kg + ((size_t)(b*S + nk))*D + h*HD;
    float sdot = 0.f;
    #pragma unroll
    for (int c4 = 0; c4 < 4; ++c4) {
      u16x8 kv = *(const u16x8*)(krow + c4*8);
      #pragma unroll
      for (int j = 0; j < 8; ++j) sdot += qs[h*HD + c4*8 + j] * b2f(kv[j]);
    }
    sc[h*CAP + n] = sdot * scale + nbias[n];
  }
  __syncthreads();

  // per-head softmax (32 lanes per head) + weighted V gather
  const int h = t >> 5, dd = t & 31;
  float outv;
  if (cnt > 0) {
    float m = -1e30f;
    for (int n = dd; n < cnt; n += 32) m = fmaxf(m, sc[h*CAP + n]);
    #pragma unroll
    for (int off=16; off>=1; off>>=1) m = fmaxf(m, __shfl_xor(m, off, 64));
    float sum = 0.f;
    for (int n = dd; n < cnt; n += 32) {
      float e = __expf(sc[h*CAP + n] - m);
      sc[h*CAP + n] = e;
      sum += e;
    }
    #pragma unroll
    for (int off=16; off>=1; off>>=1) sum += __shfl_xor(sum, off, 64);
    __syncthreads();
    float a = 0.f;
    const unsigned short* vbase = vg + (size_t)b*S*D + h*HD + dd;
    for (int n = 0; n < cnt; ++n)
      a += sc[h*CAP + n] * b2f(vbase[(size_t)nidx[n] * D]);
    outv = a / sum;
  } else {
    // fully-masked row: reference softmax degenerates to uniform 1/S
    float a = 0.f;
    const unsigned short* vbase = vg + (size_t)b*S*D + h*HD + dd;
    for (int n = 0; n < S; ++n) a += b2f(vbase[(size_t)n * D]);
    outv = a * (1.f / S);
  }
  ctx[(size_t)bqi * D + t] = f2b(outv);
}

extern "C" void kernel_launch(void* const* d_in, const int* in_sizes, int n_in,
                              void* d_out, int out_size, void* d_ws, size_t ws_size,
                              hipStream_t stream) {
  const float*          x    = (const float*)d_in[0];
  const int*            mask = (const int*)d_in[1];
  const float*          eat  = (const float*)d_in[2];
  const int*            eidx = (const int*)d_in[3];
  const float*          ln1g = (const float*)d_in[4];
  const float*          ln1b = (const float*)d_in[5];
  const float*          wq   = (const float*)d_in[6];
  const float*          bq   = (const float*)d_in[7];
  const float*          wk   = (const float*)d_in[8];
  const float*          bk   = (const float*)d_in[9];
  const float*          wv   = (const float*)d_in[10];
  const float*          bv   = (const float*)d_in[11];
  const float*          wo   = (const float*)d_in[12];
  const float*          bo   = (const float*)d_in[13];
  const float*          ln2g = (const float*)d_in[14];
  const float*          ln2b = (const float*)d_in[15];
  const float*          w1   = (const float*)d_in[16];
  const float*          b1   = (const float*)d_in[17];
  const float*          w2   = (const float*)d_in[18];
  const float*          b2   = (const float*)d_in[19];
  float* out = (float*)d_out;

  // workspace layout (element offsets)
  char* ws = (char*)d_ws;
  unsigned short* nx  = (unsigned short*)ws;                    // 4MB, reused as n2
  unsigned short* qb  = nx + (size_t)M_TOK*D;                   // 4MB
  unsigned short* kbf = qb + (size_t)M_TOK*D;                   // 4MB
  unsigned short* vbf = kbf + (size_t)M_TOK*D;                  // 4MB
  unsigned short* cx  = vbf + (size_t)M_TOK*D;                  // 4MB
  float*          x1  = (float*)(cx + (size_t)M_TOK*D);         // 8MB
  unsigned int*   pk  = (unsigned int*)(x1 + (size_t)M_TOK*D);  // 16MB
  unsigned short* wqb = (unsigned short*)(pk + (size_t)S*S);    // 128KB
  unsigned short* wkb = wqb + (size_t)D*D;                      // 128KB
  unsigned short* wvb = wkb + (size_t)D*D;                      // 128KB
  unsigned short* wob = wvb + (size_t)D*D;                      // 128KB
  unsigned short* w1b = wob + (size_t)D*D;                      // 512KB
  unsigned short* w2b = w1b + (size_t)DFF*D;                    // 512KB
  unsigned short* hb  = qb;   // overlay: q/k/v/cx (16MB) dead by MLP1
  unsigned short* n2  = nx;   // overlay: nx dead by LN2

  cvt_kernel<<<D*D/4/256,   256, 0, stream>>>(wq, wqb, D*D/4);
  cvt_kernel<<<D*D/4/256,   256, 0, stream>>>(wk, wkb, D*D/4);
  cvt_kernel<<<D*D/4/256,   256, 0, stream>>>(wv, wvb, D*D/4);
  cvt_kernel<<<D*D/4/256,   256, 0, stream>>>(wo, wob, D*D/4);
  cvt_kernel<<<DFF*D/4/256, 256, 0, stream>>>(w1, w1b, DFF*D/4);
  cvt_kernel<<<DFF*D/4/256, 256, 0, stream>>>(w2, w2b, DFF*D/4);

  zero_kernel<<<(S*S/4 + 255)/256, 256, 0, stream>>>((uint4*)pk, S*S/4);
  scatter_kernel<<<E_EDGES/256, 256, 0, stream>>>(eidx, eat, pk);
  ln_kernel<<<M_TOK/4, 256, 0, stream>>>(x, ln1g, ln1b, nx);
  gemm_kernel<<<dim3(D/64,  M_TOK/64), 256, 0, stream>>>(nx, wqb, bq, qb, nullptr, nullptr, M_TOK, D, D, 0);
  gemm_kernel<<<dim3(D/64,  M_TOK/64), 256, 0, stream>>>(nx, wkb, bk, kbf, nullptr, nullptr, M_TOK, D, D, 0);
  gemm_kernel<<<dim3(D/64,  M_TOK/64), 256, 0, stream>>>(nx, wvb, bv, vbf, nullptr, nullptr, M_TOK, D, D, 0);
  attn_kernel<<<M_TOK, 256, 0, stream>>>(qb, kbf, vbf, mask, pk, cx);
  gemm_kernel<<<dim3(D/64,  M_TOK/64), 256, 0, stream>>>(cx, wob, bo, nullptr, x1, x, M_TOK, D, D, 0);
  ln_kernel<<<M_TOK/4, 256, 0, stream>>>(x1, ln2g, ln2b, n2);
  gemm_kernel<<<dim3(DFF/64, M_TOK/64), 256, 0, stream>>>(n2, w1b, b1, hb, nullptr, nullptr, M_TOK, DFF, D, 1);
  gemm_kernel<<<dim3(D/64,  M_TOK/64), 256, 0, stream>>>(hb, w2b, b2, nullptr, out, x1, M_TOK, D, DFF, 0);
}